// Round 1
// baseline (536.642 us; speedup 1.0000x reference)
//
#include <hip/hip_runtime.h>
#include <hip/hip_bf16.h>
#include <math.h>

#define NN 50000
#define NE 800000
#define NK 4
#define FD 128
#define CD 32
#define NCHUNK 196   // ceil(NN/256)
#define BNCH 25      // bn stat chunks
#define BNROWS 2000  // rows per bn chunk (25*2000 = 50000)

// ---------------- CSR build ----------------

__global__ void k_count(const int* __restrict__ dst, int* __restrict__ count) {
    int i = blockIdx.x * 256 + threadIdx.x;
    if (i < NE) atomicAdd(&count[dst[i]], 1);
}

__global__ void k_chunksum(const int* __restrict__ count, int* __restrict__ csum) {
    __shared__ int s[256];
    int tid = threadIdx.x;
    int i = blockIdx.x * 256 + tid;
    s[tid] = (i < NN) ? count[i] : 0;
    __syncthreads();
    for (int off = 128; off > 0; off >>= 1) {
        if (tid < off) s[tid] += s[tid + off];
        __syncthreads();
    }
    if (tid == 0) csum[blockIdx.x] = s[0];
}

__global__ void k_scan_csum(int* __restrict__ csum) {
    __shared__ int s[256];
    int tid = threadIdx.x;
    int v = (tid < NCHUNK) ? csum[tid] : 0;
    s[tid] = v;
    __syncthreads();
    for (int off = 1; off < 256; off <<= 1) {
        int t = 0;
        if (tid >= off) t = s[tid - off];
        __syncthreads();
        s[tid] += t;
        __syncthreads();
    }
    if (tid < NCHUNK) csum[tid] = s[tid] - v;  // exclusive
}

__global__ void k_scan_final(const int* __restrict__ count, const int* __restrict__ csum,
                             int* __restrict__ rowstart, int* __restrict__ cursor) {
    __shared__ int s[256];
    int tid = threadIdx.x;
    int i = blockIdx.x * 256 + tid;
    int v = (i < NN) ? count[i] : 0;
    s[tid] = v;
    __syncthreads();
    for (int off = 1; off < 256; off <<= 1) {
        int t = 0;
        if (tid >= off) t = s[tid - off];
        __syncthreads();
        s[tid] += t;
        __syncthreads();
    }
    int incl = s[tid];
    int base = csum[blockIdx.x];
    int excl = base + incl - v;
    if (i < NN) {
        rowstart[i] = excl;
        cursor[i] = excl;
        if (i == NN - 1) rowstart[NN] = excl + v;
    }
}

__global__ void k_scatter(const int* __restrict__ src, const int* __restrict__ dst,
                          int* __restrict__ cursor, int* __restrict__ ssrc,
                          int* __restrict__ seid) {
    int e = blockIdx.x * 256 + threadIdx.x;
    if (e < NE) {
        int d = dst[e];
        int p = atomicAdd(&cursor[d], 1);
        ssrc[p] = src[e];
        seid[p] = e;
    }
}

// ---------------- encoder: out0 = x @ W + b ----------------
// block 256: 64 nodes x 128 cols; thread -> 8 nodes x 4 cols register tile.

__global__ void __launch_bounds__(256) k_encoder(const float* __restrict__ x,
                                                 const float* __restrict__ W,
                                                 const float* __restrict__ b,
                                                 float* __restrict__ out) {
    __shared__ float xsT[FD][68];  // [f][node], stride 68 dwords (16B-aligned rows, bank-spread)
    int tid = threadIdx.x;
    int nbase = blockIdx.x * 64;

    int r = tid >> 2;           // 0..63 node within tile
    int cg = (tid & 3) * 32;    // col group of 32
    int gn = nbase + r;
    const float* xr = x + (size_t)(gn < NN ? gn : NN - 1) * FD;
#pragma unroll
    for (int q = 0; q < 8; ++q) {
        float4 v = *(const float4*)(xr + cg + q * 4);
        int f = cg + q * 4;
        xsT[f][r] = v.x; xsT[f + 1][r] = v.y; xsT[f + 2][r] = v.z; xsT[f + 3][r] = v.w;
    }
    __syncthreads();

    int cq = (tid & 31) * 4;  // cols cq..cq+3
    int g = tid >> 5;         // node group: nodes g*8 .. g*8+7
    float acc[8][4];
#pragma unroll
    for (int i = 0; i < 8; ++i)
#pragma unroll
        for (int j = 0; j < 4; ++j) acc[i][j] = 0.f;

    for (int f = 0; f < FD; ++f) {
        float4 wv = *(const float4*)(W + f * FD + cq);
        float4 xa = *(const float4*)&xsT[f][g * 8];
        float4 xb = *(const float4*)&xsT[f][g * 8 + 4];
        float xn[8] = {xa.x, xa.y, xa.z, xa.w, xb.x, xb.y, xb.z, xb.w};
#pragma unroll
        for (int i = 0; i < 8; ++i) {
            acc[i][0] += xn[i] * wv.x;
            acc[i][1] += xn[i] * wv.y;
            acc[i][2] += xn[i] * wv.z;
            acc[i][3] += xn[i] * wv.w;
        }
    }
    float4 bv = *(const float4*)(b + cq);
#pragma unroll
    for (int i = 0; i < 8; ++i) {
        int n = nbase + g * 8 + i;
        if (n < NN) {
            float4 o;
            o.x = acc[i][0] + bv.x;
            o.y = acc[i][1] + bv.y;
            o.z = acc[i][2] + bv.z;
            o.w = acc[i][3] + bv.w;
            *(float4*)(out + (size_t)n * FD + cq) = o;
        }
    }
}

// ---------------- layer 0: h = x (128 feats), all 4 communities in one pass ----------------
// one wave per node; lane owns 2 features.

__global__ void __launch_bounds__(64) k_layer0(const float* __restrict__ x,
                                               const int* __restrict__ row,
                                               const int* __restrict__ ssrc,
                                               const int* __restrict__ seid,
                                               const float* __restrict__ ew,
                                               const float* __restrict__ W1,
                                               const float* __restrict__ b1,
                                               const float* __restrict__ W2,
                                               const float* __restrict__ b2,
                                               float* __restrict__ u) {
    int node = blockIdx.x;
    int lane = threadIdx.x;
    __shared__ float zsh[NK][FD];
    __shared__ float tsh[NK * CD];

    int c0 = lane * 2;
    float2 xv = *(const float2*)(x + (size_t)node * FD + c0);
    float a[NK][2];
#pragma unroll
    for (int k = 0; k < NK; ++k) { a[k][0] = 0.f; a[k][1] = 0.f; }

    int beg = row[node], end = row[node + 1];
    for (int j = beg; j < end; ++j) {
        int s = ssrc[j];
        int e = seid[j];
        float2 v = *(const float2*)(x + (size_t)s * FD + c0);
#pragma unroll
        for (int k = 0; k < NK; ++k) {
            float w = ew[(size_t)k * NE + e];
            a[k][0] += w * v.x;
            a[k][1] += w * v.y;
        }
    }
#pragma unroll
    for (int k = 0; k < NK; ++k) {
        zsh[k][c0] = xv.x + a[k][0];
        zsh[k][c0 + 1] = xv.y + a[k][1];
    }
    __syncthreads();

    // MLP: t = relu(z @ W1 + b1); u = t @ W2 + b2. lane computes (kA,j0) and (kB,j0).
    int j0 = lane & 31;
    int kA = lane >> 5;   // 0 or 1
    int kB = kA + 2;      // 2 or 3
    float tA = b1[j0], tB = tA;
    for (int f = 0; f < FD; ++f) {
        float w = W1[f * CD + j0];
        tA += zsh[kA][f] * w;
        tB += zsh[kB][f] * w;
    }
    tA = fmaxf(tA, 0.f);
    tB = fmaxf(tB, 0.f);
    tsh[kA * CD + j0] = tA;
    tsh[kB * CD + j0] = tB;
    __syncthreads();
    float uA = b2[j0], uB = uA;
    for (int m = 0; m < CD; ++m) {
        float w = W2[m * CD + j0];
        uA += tsh[kA * CD + m] * w;
        uB += tsh[kB * CD + m] * w;
    }
    u[((size_t)kA * NN + node) * CD + j0] = uA;
    u[((size_t)kB * NN + node) * CD + j0] = uB;
}

// ---------------- layer 1: h = out plane 1 ([N][128], col = k*32+f) ----------------

__global__ void __launch_bounds__(64) k_layer1(const float* __restrict__ h,
                                               const int* __restrict__ row,
                                               const int* __restrict__ ssrc,
                                               const int* __restrict__ seid,
                                               const float* __restrict__ ew,
                                               const float* __restrict__ W1,
                                               const float* __restrict__ b1,
                                               const float* __restrict__ W2,
                                               const float* __restrict__ b2,
                                               float* __restrict__ u) {
    int node = blockIdx.x;
    int lane = threadIdx.x;
    __shared__ float zsh[FD];  // col = k*32+f
    __shared__ float tsh[FD];

    int c0 = lane * 2;
    int kk = c0 >> 5;  // community of this lane's columns
    float2 hv = *(const float2*)(h + (size_t)node * FD + c0);
    float a0 = 0.f, a1 = 0.f;
    int beg = row[node], end = row[node + 1];
    const float* ewk = ew + (size_t)kk * NE;
    for (int j = beg; j < end; ++j) {
        int s = ssrc[j];
        int e = seid[j];
        float2 v = *(const float2*)(h + (size_t)s * FD + c0);
        float w = ewk[e];
        a0 += w * v.x;
        a1 += w * v.y;
    }
    zsh[c0] = hv.x + a0;
    zsh[c0 + 1] = hv.y + a1;
    __syncthreads();

    int j0 = lane & 31;
    int kA = lane >> 5, kB = kA + 2;
    float tA = b1[j0], tB = tA;
    for (int m = 0; m < CD; ++m) {
        float w = W1[m * CD + j0];
        tA += zsh[kA * CD + m] * w;
        tB += zsh[kB * CD + m] * w;
    }
    tA = fmaxf(tA, 0.f);
    tB = fmaxf(tB, 0.f);
    tsh[kA * CD + j0] = tA;
    tsh[kB * CD + j0] = tB;
    __syncthreads();
    float uA = b2[j0], uB = uA;
    for (int m = 0; m < CD; ++m) {
        float w = W2[m * CD + j0];
        uA += tsh[kA * CD + m] * w;
        uB += tsh[kB * CD + m] * w;
    }
    u[((size_t)kA * NN + node) * CD + j0] = uA;
    u[((size_t)kB * NN + node) * CD + j0] = uB;
}

// ---------------- batchnorm stats (two-stage, deterministic) ----------------

__global__ void __launch_bounds__(256) k_bn_stats1(const float* __restrict__ u,
                                                   float* __restrict__ part) {
    int k = blockIdx.x & 3;
    int ch = blockIdx.x >> 2;
    int f = threadIdx.x & 31;
    int rg = threadIdx.x >> 5;  // 0..7
    float s1 = 0.f, s2 = 0.f;
    int nend = (ch + 1) * BNROWS;
    if (nend > NN) nend = NN;
    for (int n = ch * BNROWS + rg; n < nend; n += 8) {
        float v = u[((size_t)k * NN + n) * CD + f];
        s1 += v;
        s2 += v * v;
    }
    __shared__ float sh1[8][32], sh2[8][32];
    sh1[rg][f] = s1;
    sh2[rg][f] = s2;
    __syncthreads();
    if (rg == 0) {
#pragma unroll
        for (int r = 1; r < 8; ++r) {
            s1 += sh1[r][f];
            s2 += sh2[r][f];
        }
        part[(((size_t)k * BNCH + ch) * CD + f) * 2] = s1;
        part[(((size_t)k * BNCH + ch) * CD + f) * 2 + 1] = s2;
    }
}

__global__ void k_bn_stats2(const float* __restrict__ part, const float* __restrict__ gamma,
                            const float* __restrict__ beta, float* __restrict__ bnp) {
    int c = threadIdx.x;  // 0..127
    int k = c >> 5, f = c & 31;
    float S1 = 0.f, S2 = 0.f;
    for (int ch = 0; ch < BNCH; ++ch) {
        S1 += part[(((size_t)k * BNCH + ch) * CD + f) * 2];
        S2 += part[(((size_t)k * BNCH + ch) * CD + f) * 2 + 1];
    }
    float mean = S1 / (float)NN;
    float var = S2 / (float)NN - mean * mean;
    float scale = gamma[f] * rsqrtf(var + 1e-5f);
    bnp[c * 2] = scale;
    bnp[c * 2 + 1] = beta[f] - mean * scale;
}

__global__ void __launch_bounds__(256) k_bn_apply(const float* __restrict__ u,
                                                  const float* __restrict__ bnp,
                                                  float* __restrict__ out) {
    int idx = blockIdx.x * 256 + threadIdx.x;  // over NN*FD
    int n = idx >> 7;
    int c = idx & 127;
    int k = c >> 5, f = c & 31;
    float v = u[((size_t)k * NN + n) * CD + f];
    out[idx] = fmaxf(fmaf(v, bnp[c * 2], bnp[c * 2 + 1]), 0.f);
}

// ---------------- launch ----------------

extern "C" void kernel_launch(void* const* d_in, const int* in_sizes, int n_in,
                              void* d_out, int out_size, void* d_ws, size_t ws_size,
                              hipStream_t stream) {
    const float* x = (const float*)d_in[0];
    const int* ei = (const int*)d_in[1];
    const float* ew = (const float*)d_in[2];
    const float* l0W1 = (const float*)d_in[3];
    const float* l0b1 = (const float*)d_in[4];
    const float* l0W2 = (const float*)d_in[5];
    const float* l0b2 = (const float*)d_in[6];
    const float* l0g = (const float*)d_in[7];
    const float* l0be = (const float*)d_in[8];
    const float* l1W1 = (const float*)d_in[9];
    const float* l1b1 = (const float*)d_in[10];
    const float* l1W2 = (const float*)d_in[11];
    const float* l1b2 = (const float*)d_in[12];
    const float* l1g = (const float*)d_in[13];
    const float* l1be = (const float*)d_in[14];
    const float* encW = (const float*)d_in[15];
    const float* encb = (const float*)d_in[16];
    float* out = (float*)d_out;

    char* ws = (char*)d_ws;
    size_t off = 0;
    auto alloc = [&](size_t bytes) -> void* {
        void* p = ws + off;
        off += (bytes + 255) & ~(size_t)255;
        return p;
    };
    int* dcount = (int*)alloc((size_t)NN * 4);
    int* drow = (int*)alloc((size_t)(NN + 1) * 4);
    int* dcur = (int*)alloc((size_t)NN * 4);
    int* dcsum = (int*)alloc(256 * 4);
    int* dssrc = (int*)alloc((size_t)NE * 4);
    int* dseid = (int*)alloc((size_t)NE * 4);
    float* du = (float*)alloc((size_t)NK * NN * CD * 4);
    float* dpart = (float*)alloc((size_t)NK * BNCH * CD * 2 * 4);
    float* dbnp = (float*)alloc((size_t)FD * 2 * 4);

    const int* src = ei;
    const int* dst = ei + NE;

    // CSR build
    hipMemsetAsync(dcount, 0, (size_t)NN * 4, stream);
    k_count<<<(NE + 255) / 256, 256, 0, stream>>>(dst, dcount);
    k_chunksum<<<NCHUNK, 256, 0, stream>>>(dcount, dcsum);
    k_scan_csum<<<1, 256, 0, stream>>>(dcsum);
    k_scan_final<<<NCHUNK, 256, 0, stream>>>(dcount, dcsum, drow, dcur);
    k_scatter<<<(NE + 255) / 256, 256, 0, stream>>>(src, dst, dcur, dssrc, dseid);

    // plane 0: input encoder
    k_encoder<<<(NN + 63) / 64, 256, 0, stream>>>(x, encW, encb, out);

    // layer 0 -> plane 1
    float* plane1 = out + (size_t)NN * FD;
    k_layer0<<<NN, 64, 0, stream>>>(x, drow, dssrc, dseid, ew, l0W1, l0b1, l0W2, l0b2, du);
    k_bn_stats1<<<NK * BNCH, 256, 0, stream>>>(du, dpart);
    k_bn_stats2<<<1, 128, 0, stream>>>(dpart, l0g, l0be, dbnp);
    k_bn_apply<<<(NN * FD) / 256, 256, 0, stream>>>(du, dbnp, plane1);

    // layer 1 -> plane 2
    float* plane2 = out + (size_t)2 * NN * FD;
    k_layer1<<<NN, 64, 0, stream>>>(plane1, drow, dssrc, dseid, ew, l1W1, l1b1, l1W2, l1b2, du);
    k_bn_stats1<<<NK * BNCH, 256, 0, stream>>>(du, dpart);
    k_bn_stats2<<<1, 128, 0, stream>>>(dpart, l1g, l1be, dbnp);
    k_bn_apply<<<(NN * FD) / 256, 256, 0, stream>>>(du, dbnp, plane2);
}

// Round 2
// 476.840 us; speedup vs baseline: 1.1254x; 1.1254x over previous
//
#include <hip/hip_runtime.h>
#include <hip/hip_bf16.h>
#include <math.h>

#define NN 50000
#define NE 800000
#define NK 4
#define FD 128
#define CD 32
#define NCHUNK 196   // ceil(NN/256)
#define BNCH 25      // bn stat chunks
#define BNROWS 2000  // rows per bn chunk (25*2000 = 50000)

// ---------------- CSR build ----------------

__global__ void k_count(const int* __restrict__ dst, int* __restrict__ count) {
    int i = blockIdx.x * 256 + threadIdx.x;
    if (i < NE) atomicAdd(&count[dst[i]], 1);
}

__global__ void k_chunksum(const int* __restrict__ count, int* __restrict__ csum) {
    __shared__ int s[256];
    int tid = threadIdx.x;
    int i = blockIdx.x * 256 + tid;
    s[tid] = (i < NN) ? count[i] : 0;
    __syncthreads();
    for (int off = 128; off > 0; off >>= 1) {
        if (tid < off) s[tid] += s[tid + off];
        __syncthreads();
    }
    if (tid == 0) csum[blockIdx.x] = s[0];
}

__global__ void k_scan_csum(int* __restrict__ csum) {
    __shared__ int s[256];
    int tid = threadIdx.x;
    int v = (tid < NCHUNK) ? csum[tid] : 0;
    s[tid] = v;
    __syncthreads();
    for (int off = 1; off < 256; off <<= 1) {
        int t = 0;
        if (tid >= off) t = s[tid - off];
        __syncthreads();
        s[tid] += t;
        __syncthreads();
    }
    if (tid < NCHUNK) csum[tid] = s[tid] - v;  // exclusive
}

__global__ void k_scan_final(const int* __restrict__ count, const int* __restrict__ csum,
                             int* __restrict__ rowstart, int* __restrict__ cursor) {
    __shared__ int s[256];
    int tid = threadIdx.x;
    int i = blockIdx.x * 256 + tid;
    int v = (i < NN) ? count[i] : 0;
    s[tid] = v;
    __syncthreads();
    for (int off = 1; off < 256; off <<= 1) {
        int t = 0;
        if (tid >= off) t = s[tid - off];
        __syncthreads();
        s[tid] += t;
        __syncthreads();
    }
    int incl = s[tid];
    int base = csum[blockIdx.x];
    int excl = base + incl - v;
    if (i < NN) {
        rowstart[i] = excl;
        cursor[i] = excl;
        if (i == NN - 1) rowstart[NN] = excl + v;
    }
}

// scatter src ids AND pre-gather all 4 communities' edge weights into CSR order
__global__ void k_scatter(const int* __restrict__ src, const int* __restrict__ dst,
                          const float* __restrict__ ew,
                          int* __restrict__ cursor, int* __restrict__ ssrc,
                          float* __restrict__ wei) {
    int e = blockIdx.x * 256 + threadIdx.x;
    if (e < NE) {
        int d = dst[e];
        int p = atomicAdd(&cursor[d], 1);
        ssrc[p] = src[e];
#pragma unroll
        for (int k = 0; k < NK; ++k)
            wei[(size_t)k * NE + p] = ew[(size_t)k * NE + e];
    }
}

// ---------------- encoder: out0 = x @ W + b (128->128) ----------------

__global__ void __launch_bounds__(256) k_encoder(const float* __restrict__ x,
                                                 const float* __restrict__ W,
                                                 const float* __restrict__ b,
                                                 float* __restrict__ out) {
    __shared__ float xsT[FD][68];
    int tid = threadIdx.x;
    int nbase = blockIdx.x * 64;

    int r = tid >> 2;
    int cg = (tid & 3) * 32;
    int gn = nbase + r;
    const float* xr = x + (size_t)(gn < NN ? gn : NN - 1) * FD;
#pragma unroll
    for (int q = 0; q < 8; ++q) {
        float4 v = *(const float4*)(xr + cg + q * 4);
        int f = cg + q * 4;
        xsT[f][r] = v.x; xsT[f + 1][r] = v.y; xsT[f + 2][r] = v.z; xsT[f + 3][r] = v.w;
    }
    __syncthreads();

    int cq = (tid & 31) * 4;
    int g = tid >> 5;
    float acc[8][4];
#pragma unroll
    for (int i = 0; i < 8; ++i)
#pragma unroll
        for (int j = 0; j < 4; ++j) acc[i][j] = 0.f;

    for (int f = 0; f < FD; ++f) {
        float4 wv = *(const float4*)(W + f * FD + cq);
        float4 xa = *(const float4*)&xsT[f][g * 8];
        float4 xb = *(const float4*)&xsT[f][g * 8 + 4];
        float xn[8] = {xa.x, xa.y, xa.z, xa.w, xb.x, xb.y, xb.z, xb.w};
#pragma unroll
        for (int i = 0; i < 8; ++i) {
            acc[i][0] += xn[i] * wv.x;
            acc[i][1] += xn[i] * wv.y;
            acc[i][2] += xn[i] * wv.z;
            acc[i][3] += xn[i] * wv.w;
        }
    }
    float4 bv = *(const float4*)(b + cq);
#pragma unroll
    for (int i = 0; i < 8; ++i) {
        int n = nbase + g * 8 + i;
        if (n < NN) {
            float4 o;
            o.x = acc[i][0] + bv.x;
            o.y = acc[i][1] + bv.y;
            o.z = acc[i][2] + bv.z;
            o.w = acc[i][3] + bv.w;
            *(float4*)(out + (size_t)n * FD + cq) = o;
        }
    }
}

// ---------------- y0 = x @ W1 (128->32, no bias) ----------------
// 64 nodes/block; thread = (col 0..31, nodegroup 0..7 of 8 nodes)

__global__ void __launch_bounds__(256) k_y0(const float* __restrict__ x,
                                            const float* __restrict__ W1,
                                            float* __restrict__ y0) {
    __shared__ float xsT[FD][68];
    int tid = threadIdx.x;
    int nbase = blockIdx.x * 64;

    int r = tid >> 2;
    int cg = (tid & 3) * 32;
    int gn = nbase + r;
    const float* xr = x + (size_t)(gn < NN ? gn : NN - 1) * FD;
#pragma unroll
    for (int q = 0; q < 8; ++q) {
        float4 v = *(const float4*)(xr + cg + q * 4);
        int f = cg + q * 4;
        xsT[f][r] = v.x; xsT[f + 1][r] = v.y; xsT[f + 2][r] = v.z; xsT[f + 3][r] = v.w;
    }
    __syncthreads();

    int col = tid & 31;
    int g = tid >> 5;
    float acc[8];
#pragma unroll
    for (int i = 0; i < 8; ++i) acc[i] = 0.f;

    for (int f = 0; f < FD; ++f) {
        float wv = W1[f * CD + col];
        float4 xa = *(const float4*)&xsT[f][g * 8];
        float4 xb = *(const float4*)&xsT[f][g * 8 + 4];
        acc[0] += xa.x * wv; acc[1] += xa.y * wv; acc[2] += xa.z * wv; acc[3] += xa.w * wv;
        acc[4] += xb.x * wv; acc[5] += xb.y * wv; acc[6] += xb.z * wv; acc[7] += xb.w * wv;
    }
#pragma unroll
    for (int i = 0; i < 8; ++i) {
        int n = nbase + g * 8 + i;
        if (n < NN) y0[(size_t)n * CD + col] = acc[i];
    }
}

// ---------------- y1: block-diagonal per-community h_k @ W1 (32->32) ----------------
// input h [N][128] (col = k*32+f), output y1 [N][128] same layout

__global__ void __launch_bounds__(256) k_y1(const float* __restrict__ h,
                                            const float* __restrict__ W1,
                                            float* __restrict__ y1) {
    __shared__ float hsT[FD][68];
    int tid = threadIdx.x;
    int nbase = blockIdx.x * 64;

    int r = tid >> 2;
    int cg = (tid & 3) * 32;
    int gn = nbase + r;
    const float* hr = h + (size_t)(gn < NN ? gn : NN - 1) * FD;
#pragma unroll
    for (int q = 0; q < 8; ++q) {
        float4 v = *(const float4*)(hr + cg + q * 4);
        int f = cg + q * 4;
        hsT[f][r] = v.x; hsT[f + 1][r] = v.y; hsT[f + 2][r] = v.z; hsT[f + 3][r] = v.w;
    }
    __syncthreads();

    int c0 = (tid & 31) * 4;   // output cols c0..c0+3 (within one community)
    int g = tid >> 5;
    int kc = c0 >> 5;          // community
    int jb = c0 & 31;          // col within community
    float acc[8][4];
#pragma unroll
    for (int i = 0; i < 8; ++i)
#pragma unroll
        for (int j = 0; j < 4; ++j) acc[i][j] = 0.f;

    for (int m = 0; m < CD; ++m) {
        float4 wv = *(const float4*)(W1 + m * CD + jb);
        float4 xa = *(const float4*)&hsT[kc * CD + m][g * 8];
        float4 xb = *(const float4*)&hsT[kc * CD + m][g * 8 + 4];
        float xn[8] = {xa.x, xa.y, xa.z, xa.w, xb.x, xb.y, xb.z, xb.w};
#pragma unroll
        for (int i = 0; i < 8; ++i) {
            acc[i][0] += xn[i] * wv.x;
            acc[i][1] += xn[i] * wv.y;
            acc[i][2] += xn[i] * wv.z;
            acc[i][3] += xn[i] * wv.w;
        }
    }
#pragma unroll
    for (int i = 0; i < 8; ++i) {
        int n = nbase + g * 8 + i;
        if (n < NN) {
            float4 o = {acc[i][0], acc[i][1], acc[i][2], acc[i][3]};
            *(float4*)(y1 + (size_t)n * FD + c0) = o;
        }
    }
}

// ---------------- fused aggregation + relu + MLP2 ----------------
// STRIDE=32: y is y0 [N][32] shared across communities (layer 0)
// STRIDE=128: y is y1 [N][128] community-interleaved (layer 1)
// 4 nodes per block (1 wave each). lane: k = lane>>4, f0 = (lane&15)*2.
// t_k = relu(y[n] + sum_j w_k(j) y[src_j] + b1); u_k = t_k @ W2 + b2 -> u [4][N][32]

template <int STRIDE>
__global__ void __launch_bounds__(256) k_aggr(const float* __restrict__ y,
                                              const int* __restrict__ row,
                                              const int* __restrict__ ssrc,
                                              const float* __restrict__ wei,
                                              const float* __restrict__ b1,
                                              const float* __restrict__ W2,
                                              const float* __restrict__ b2,
                                              float* __restrict__ u) {
    __shared__ float tsh[4][NK][CD + 1];
    __shared__ float W2s[CD][CD];
    __shared__ float b2s[CD];
    int tid = threadIdx.x;
    for (int i = tid; i < CD * CD; i += 256) W2s[i >> 5][i & 31] = W2[i];
    if (tid < CD) b2s[tid] = b2[tid];
    __syncthreads();

    int w = tid >> 6;
    int lane = tid & 63;
    int node = blockIdx.x * 4 + w;   // NN divisible by 4

    int k = lane >> 4;
    int f0 = (lane & 15) * 2;
    int col = (STRIDE == CD) ? f0 : lane * 2;
    const float* yb = y + col;
    const float* wk = wei + (size_t)k * NE;

    float a0 = 0.f, a1 = 0.f;
    int beg = row[node], end = row[node + 1];
    for (int j0 = beg; j0 < end; j0 += 8) {
        int sreg[8];
        float wreg[8];
#pragma unroll
        for (int q = 0; q < 8; ++q) {
            int jj = j0 + q;
            bool ok = jj < end;
            int jc = ok ? jj : beg;
            sreg[q] = ssrc[jc];
            wreg[q] = ok ? wk[jc] : 0.f;
        }
#pragma unroll
        for (int q = 0; q < 8; ++q) {
            float2 v = *(const float2*)(yb + (size_t)sreg[q] * STRIDE);
            a0 += wreg[q] * v.x;
            a1 += wreg[q] * v.y;
        }
    }
    float2 hv = *(const float2*)(yb + (size_t)node * STRIDE);
    float2 bv = *(const float2*)(b1 + f0);
    tsh[w][k][f0]     = fmaxf(hv.x + a0 + bv.x, 0.f);
    tsh[w][k][f0 + 1] = fmaxf(hv.y + a1 + bv.y, 0.f);
    __threadfence_block();  // wave-local LDS visibility (no cross-wave sharing)

    int j = lane & 31;
    int kA = lane >> 5, kB = kA + 2;
    float uA = b2s[j], uB = uA;
#pragma unroll 4
    for (int m = 0; m < CD; ++m) {
        float w2 = W2s[m][j];
        uA += tsh[w][kA][m] * w2;
        uB += tsh[w][kB][m] * w2;
    }
    u[((size_t)kA * NN + node) * CD + j] = uA;
    u[((size_t)kB * NN + node) * CD + j] = uB;
}

// ---------------- batchnorm (two-stage, deterministic) ----------------

__global__ void __launch_bounds__(256) k_bn_stats1(const float* __restrict__ u,
                                                   float* __restrict__ part) {
    int k = blockIdx.x & 3;
    int ch = blockIdx.x >> 2;
    int f = threadIdx.x & 31;
    int rg = threadIdx.x >> 5;
    float s1 = 0.f, s2 = 0.f;
    int nend = (ch + 1) * BNROWS;
    if (nend > NN) nend = NN;
    for (int n = ch * BNROWS + rg; n < nend; n += 8) {
        float v = u[((size_t)k * NN + n) * CD + f];
        s1 += v;
        s2 += v * v;
    }
    __shared__ float sh1[8][32], sh2[8][32];
    sh1[rg][f] = s1;
    sh2[rg][f] = s2;
    __syncthreads();
    if (rg == 0) {
#pragma unroll
        for (int r = 1; r < 8; ++r) {
            s1 += sh1[r][f];
            s2 += sh2[r][f];
        }
        part[(((size_t)k * BNCH + ch) * CD + f) * 2] = s1;
        part[(((size_t)k * BNCH + ch) * CD + f) * 2 + 1] = s2;
    }
}

__global__ void k_bn_stats2(const float* __restrict__ part, const float* __restrict__ gamma,
                            const float* __restrict__ beta, float* __restrict__ bnp) {
    int c = threadIdx.x;  // 0..127
    int k = c >> 5, f = c & 31;
    float S1 = 0.f, S2 = 0.f;
    for (int ch = 0; ch < BNCH; ++ch) {
        S1 += part[(((size_t)k * BNCH + ch) * CD + f) * 2];
        S2 += part[(((size_t)k * BNCH + ch) * CD + f) * 2 + 1];
    }
    float mean = S1 / (float)NN;
    float var = S2 / (float)NN - mean * mean;
    float scale = gamma[f] * rsqrtf(var + 1e-5f);
    bnp[c * 2] = scale;
    bnp[c * 2 + 1] = beta[f] - mean * scale;
}

__global__ void __launch_bounds__(256) k_bn_apply(const float* __restrict__ u,
                                                  const float* __restrict__ bnp,
                                                  float* __restrict__ out) {
    int idx = blockIdx.x * 256 + threadIdx.x;  // over NN*FD
    int n = idx >> 7;
    int c = idx & 127;
    int k = c >> 5, f = c & 31;
    float v = u[((size_t)k * NN + n) * CD + f];
    out[idx] = fmaxf(fmaf(v, bnp[c * 2], bnp[c * 2 + 1]), 0.f);
}

// ---------------- launch ----------------

extern "C" void kernel_launch(void* const* d_in, const int* in_sizes, int n_in,
                              void* d_out, int out_size, void* d_ws, size_t ws_size,
                              hipStream_t stream) {
    const float* x = (const float*)d_in[0];
    const int* ei = (const int*)d_in[1];
    const float* ew = (const float*)d_in[2];
    const float* l0W1 = (const float*)d_in[3];
    const float* l0b1 = (const float*)d_in[4];
    const float* l0W2 = (const float*)d_in[5];
    const float* l0b2 = (const float*)d_in[6];
    const float* l0g = (const float*)d_in[7];
    const float* l0be = (const float*)d_in[8];
    const float* l1W1 = (const float*)d_in[9];
    const float* l1b1 = (const float*)d_in[10];
    const float* l1W2 = (const float*)d_in[11];
    const float* l1b2 = (const float*)d_in[12];
    const float* l1g = (const float*)d_in[13];
    const float* l1be = (const float*)d_in[14];
    const float* encW = (const float*)d_in[15];
    const float* encb = (const float*)d_in[16];
    float* out = (float*)d_out;

    char* ws = (char*)d_ws;
    size_t off = 0;
    auto alloc = [&](size_t bytes) -> void* {
        void* p = ws + off;
        off += (bytes + 255) & ~(size_t)255;
        return p;
    };
    int* dcount = (int*)alloc((size_t)NN * 4);
    int* drow = (int*)alloc((size_t)(NN + 1) * 4);
    int* dcur = (int*)alloc((size_t)NN * 4);
    int* dcsum = (int*)alloc(256 * 4);
    int* dssrc = (int*)alloc((size_t)NE * 4);
    float* dwei = (float*)alloc((size_t)NK * NE * 4);
    float* dy = (float*)alloc((size_t)NN * FD * 4);   // y0 (N*32 used) / u for layer1
    float* du = (float*)alloc((size_t)NK * NN * CD * 4);  // u for layer0 / y1 for layer1
    float* dpart = (float*)alloc((size_t)NK * BNCH * CD * 2 * 4);
    float* dbnp = (float*)alloc((size_t)FD * 2 * 4);

    const int* src = ei;
    const int* dst = ei + NE;

    // CSR build + weight pre-gather
    hipMemsetAsync(dcount, 0, (size_t)NN * 4, stream);
    k_count<<<(NE + 255) / 256, 256, 0, stream>>>(dst, dcount);
    k_chunksum<<<NCHUNK, 256, 0, stream>>>(dcount, dcsum);
    k_scan_csum<<<1, 256, 0, stream>>>(dcsum);
    k_scan_final<<<NCHUNK, 256, 0, stream>>>(dcount, dcsum, drow, dcur);
    k_scatter<<<(NE + 255) / 256, 256, 0, stream>>>(src, dst, ew, dcur, dssrc, dwei);

    // plane 0: input encoder
    k_encoder<<<(NN + 63) / 64, 256, 0, stream>>>(x, encW, encb, out);

    // ---- layer 0 -> plane 1 ----
    float* plane1 = out + (size_t)NN * FD;
    k_y0<<<(NN + 63) / 64, 256, 0, stream>>>(x, l0W1, dy);
    k_aggr<CD><<<NN / 4, 256, 0, stream>>>(dy, drow, dssrc, dwei, l0b1, l0W2, l0b2, du);
    k_bn_stats1<<<NK * BNCH, 256, 0, stream>>>(du, dpart);
    k_bn_stats2<<<1, 128, 0, stream>>>(dpart, l0g, l0be, dbnp);
    k_bn_apply<<<(NN * FD) / 256, 256, 0, stream>>>(du, dbnp, plane1);

    // ---- layer 1 -> plane 2 ----
    float* plane2 = out + (size_t)2 * NN * FD;
    k_y1<<<(NN + 63) / 64, 256, 0, stream>>>(plane1, l1W1, du);   // y1 -> du [N][128]
    k_aggr<FD><<<NN / 4, 256, 0, stream>>>(du, drow, dssrc, dwei, l1b1, l1W2, l1b2, dy);
    k_bn_stats1<<<NK * BNCH, 256, 0, stream>>>(dy, dpart);
    k_bn_stats2<<<1, 128, 0, stream>>>(dpart, l1g, l1be, dbnp);
    k_bn_apply<<<(NN * FD) / 256, 256, 0, stream>>>(dy, dbnp, plane2);
}